// Round 4
// baseline (108.030 us; speedup 1.0000x reference)
//
#include <hip/hip_runtime.h>
#include <hip/hip_bf16.h>

typedef __bf16 bf16x8 __attribute__((ext_vector_type(8)));
typedef __bf16 bf16x4 __attribute__((ext_vector_type(4)));
typedef float  f32x4  __attribute__((ext_vector_type(4)));

constexpr int Bn = 8192, Dn = 64, On = 256;

// ---- prep: betasT bf16 [O][e][d] (A-operand layout) + NEGATED c_proj fp32 ----
__global__ void k_prep_beta(const float* __restrict__ betas, const float* __restrict__ centers,
                            __bf16* __restrict__ bT, float* __restrict__ ncproj) {
    __shared__ float s[64 * 65];                        // +1 pad: conflict-free transpose
    const int o = blockIdx.x, tid = threadIdx.x;
    const float* bo = betas + (size_t)o * 4096;         // betas[o][d][e]
    for (int j = tid; j < 1024; j += 256) {             // float4 quads over [d][e]
        int d = j >> 4, e = (j & 15) * 4;
        float4 v = ((const float4*)bo)[j];
        s[d * 65 + e + 0] = v.x; s[d * 65 + e + 1] = v.y;
        s[d * 65 + e + 2] = v.z; s[d * 65 + e + 3] = v.w;
    }
    __syncthreads();
    for (int j = tid; j < 1024; j += 256) {             // quads over [e][d]
        int e = j >> 4, d = (j & 15) * 4;
        bf16x4 r;
        r[0] = (__bf16)s[(d + 0) * 65 + e]; r[1] = (__bf16)s[(d + 1) * 65 + e];
        r[2] = (__bf16)s[(d + 2) * 65 + e]; r[3] = (__bf16)s[(d + 3) * 65 + e];
        *(bf16x4*)(bT + (size_t)o * 4096 + e * 64 + d) = r;
    }
    if (tid < 64) {
        float acc = 0.f;
        for (int d = 0; d < 64; ++d) acc += s[d * 65 + tid] * centers[o * 64 + d];
        ncproj[o * 64 + tid] = -acc;                    // negated: MFMA C-init
    }
}

struct AFrag { bf16x8 a[4][2]; f32x4 c[4]; };

__device__ __forceinline__ void load_afrag(AFrag& f, const __bf16* aptr, const float* cptr,
                                           int oi) {
    const __bf16* p = aptr + (size_t)oi * 4096;
    const float*  c = cptr + oi * 64;
#pragma unroll
    for (int mi = 0; mi < 4; ++mi) {
        f.a[mi][0] = *(const bf16x8*)(p + mi * 1024);
        f.a[mi][1] = *(const bf16x8*)(p + mi * 1024 + 32);
        f.c[mi]    = *(const f32x4*)(c + mi * 16);
    }
}

// ---- main: NO LDS, NO barriers. Wave = 128 b x 8 o. x-frags VGPR-resident,
//      A-frags ping-pong software-pipelined from L2. ----
__global__ __launch_bounds__(256, 2) void k_main(const float* __restrict__ x,
                                                 const __bf16* __restrict__ bT,
                                                 const float* __restrict__ ncproj,
                                                 float* __restrict__ out) {
    const int tid  = threadIdx.x;
    const int wq   = tid >> 6, lane = tid & 63;
    const int col  = lane & 15, grp = lane >> 4;
    const int bbase = blockIdx.x * 512 + wq * 128;
    const int o0    = blockIdx.y * 8;

    // x fragments: B[k=d][n=b], lane holds x[b=nf*16+col][grp*8 + ks*32 ..+7]
    // 16 x bf16x8 = 64 VGPR, loaded once, reused for all 8 o's. Coalesced:
    // one nf covers 16 consecutive 256B rows.
    bf16x8 xf[8][2];
#pragma unroll
    for (int nf = 0; nf < 8; ++nf) {
        const float* xp = x + (size_t)(bbase + nf * 16 + col) * 64 + grp * 8;
#pragma unroll
        for (int ks = 0; ks < 2; ++ks) {
            float4 v0 = *(const float4*)(xp + ks * 32);
            float4 v1 = *(const float4*)(xp + ks * 32 + 4);
            bf16x8 f;
            f[0] = (__bf16)v0.x; f[1] = (__bf16)v0.y; f[2] = (__bf16)v0.z; f[3] = (__bf16)v0.w;
            f[4] = (__bf16)v1.x; f[5] = (__bf16)v1.y; f[6] = (__bf16)v1.z; f[7] = (__bf16)v1.w;
            xf[nf][ks] = f;
        }
    }

    const __bf16* aptr = bT + (size_t)o0 * 4096 + (size_t)col * 64 + grp * 8;
    const float*  cptr = ncproj + o0 * 64 + grp * 4;

    AFrag f0, f1;
    load_afrag(f0, aptr, cptr, 0);

#pragma unroll
    for (int oi = 0; oi < 8; oi += 2) {
        if (oi + 1 < 8) load_afrag(f1, aptr, cptr, oi + 1);       // prefetch odd
        // ---- compute even oi with f0 ----
        {
            float qp[8];
#pragma unroll
            for (int nf = 0; nf < 8; ++nf) {
                f32x4 qv = {0.f, 0.f, 0.f, 0.f};
#pragma unroll
                for (int mi = 0; mi < 4; ++mi) {
                    f32x4 acc = f0.c[mi];               // C-init = -cp
                    acc = __builtin_amdgcn_mfma_f32_16x16x32_bf16(f0.a[mi][0], xf[nf][0], acc, 0, 0, 0);
                    acc = __builtin_amdgcn_mfma_f32_16x16x32_bf16(f0.a[mi][1], xf[nf][1], acc, 0, 0, 0);
                    qv += acc * acc;
                }
                qp[nf] = (qv[0] + qv[1]) + (qv[2] + qv[3]);
            }
#pragma unroll
            for (int nf = 0; nf < 8; ++nf) {
                float qs = qp[nf];
                qs += __shfl_xor(qs, 16, 64);
                qs += __shfl_xor(qs, 32, 64);
                if (grp == (nf & 3))
                    out[(size_t)(bbase + nf * 16 + col) * 256 + (o0 + oi)] = __expf(-qs);
            }
        }
        if (oi + 2 < 8) load_afrag(f0, aptr, cptr, oi + 2);       // prefetch next even
        // ---- compute odd oi with f1 ----
        if (oi + 1 < 8) {
            float qp[8];
#pragma unroll
            for (int nf = 0; nf < 8; ++nf) {
                f32x4 qv = {0.f, 0.f, 0.f, 0.f};
#pragma unroll
                for (int mi = 0; mi < 4; ++mi) {
                    f32x4 acc = f1.c[mi];
                    acc = __builtin_amdgcn_mfma_f32_16x16x32_bf16(f1.a[mi][0], xf[nf][0], acc, 0, 0, 0);
                    acc = __builtin_amdgcn_mfma_f32_16x16x32_bf16(f1.a[mi][1], xf[nf][1], acc, 0, 0, 0);
                    qv += acc * acc;
                }
                qp[nf] = (qv[0] + qv[1]) + (qv[2] + qv[3]);
            }
#pragma unroll
            for (int nf = 0; nf < 8; ++nf) {
                float qs = qp[nf];
                qs += __shfl_xor(qs, 16, 64);
                qs += __shfl_xor(qs, 32, 64);
                if (grp == (nf & 3))
                    out[(size_t)(bbase + nf * 16 + col) * 256 + (o0 + oi + 1)] = __expf(-qs);
            }
        }
    }
}

extern "C" void kernel_launch(void* const* d_in, const int* in_sizes, int n_in,
                              void* d_out, int out_size, void* d_ws, size_t ws_size,
                              hipStream_t stream) {
    const float* x       = (const float*)d_in[0];   // [8192,64]
    const float* centers = (const float*)d_in[1];   // [256,1,64]
    const float* betas   = (const float*)d_in[2];   // [256,64,64]
    float* out = (float*)d_out;                     // [8192,256] fp32

    char* ws = (char*)d_ws;
    __bf16* bT   = (__bf16*)ws;                     // 2 MB
    float*  ncpj = (float*)(ws + 2 * (1 << 20));    // 64 KB

    k_prep_beta<<<dim3(On),               dim3(256), 0, stream>>>(betas, centers, bT, ncpj);
    k_main     <<<dim3(Bn / 512, On / 8), dim3(256), 0, stream>>>(x, bT, ncpj, out);
}